// Round 7
// baseline (329.350 us; speedup 1.0000x reference)
//
#include <hip/hip_runtime.h>

// CrossAttention: B=16, Sq=4096, Dm=512, Skv=77, Dc=768, H=8, Dh=64, inner=512
// Single-pass fp16 MFMA pipeline.
//   0. pad_fill : zero vT si-pad + kbuf row-pad
//   1. cvt_h16  : x fp32 -> fp16                                   (ws, reused)
//   2. transpose_h16: W* fp32 [K][N] -> fp16 [N][K]                (ws)
//   3. gemm_ctx OUT_H : k = ctx@Wk -> fp16 [1240pad][512]          (ws)
//      gemm_ctx OUT_HT: v = ctx@Wv -> Vt fp16 [16][512][96pad]     (ws)
//   4. gemm_h16_256 OUT_H : q = xh@Wq -> fp16 [65536][512]         (d_out)
//   5. attn_h16: MFMA scores + in-reg fp32 softmax + MFMA PV       (ws)
//   6. gemm_h16_256 OUT_F32+bias: out = attn@Wout + bout -> fp32   (d_out)
// Big GEMM: 256x256 tile, BK=32, 8 waves, dbuf global_load_lds with COUNTED
// vmcnt(4) (never drained to 0 in the loop) + raw s_barrier + setprio (T3/T4/T5).

typedef unsigned short u16;
typedef unsigned int u32;
typedef _Float16 f16;
typedef __attribute__((ext_vector_type(8))) _Float16 half8;
typedef __attribute__((ext_vector_type(4))) _Float16 half4;
typedef __attribute__((ext_vector_type(4))) float f32x4;

__device__ __forceinline__ f32x4 mfma16h(half8 a, half8 b, f32x4 c) {
    return __builtin_amdgcn_mfma_f32_16x16x32_f16(a, b, c, 0, 0, 0);
}
// async global->LDS, 16B per lane; LDS dest = wave-uniform base + lane*16
__device__ __forceinline__ void gl_lds16(const f16* g, f16* l) {
    __builtin_amdgcn_global_load_lds(
        (const __attribute__((address_space(1))) void*)g,
        (__attribute__((address_space(3))) void*)l, 16, 0, 0);
}

// ---------------- pad fill ----------------
__global__ __launch_bounds__(256) void pad_fill(
    f16* __restrict__ vT, f16* __restrict__ kbuf)
{
    const int nv = 16 * 512 * 19;
    int i = blockIdx.x * 256 + threadIdx.x;
    if (i < nv) {
        int g = i / 19, s = i - g * 19;
        vT[(size_t)g * 96 + 77 + s] = (f16)0.f;
    } else {
        int j = i - nv;
        if (j < 8 * 512) kbuf[(size_t)1232 * 512 + j] = (f16)0.f;
    }
}

// ---------------- x -> fp16 (elementwise) ----------------
__global__ __launch_bounds__(256) void cvt_h16(
    const float* __restrict__ x, f16* __restrict__ xh, long n8)
{
    long i = blockIdx.x * 256 + threadIdx.x;
    const long stride = (long)gridDim.x * 256;
    for (; i < n8; i += stride) {
        float4 a = ((const float4*)x)[2 * i];
        float4 b = ((const float4*)x)[2 * i + 1];
        half8 h = { (f16)a.x, (f16)a.y, (f16)a.z, (f16)a.w,
                    (f16)b.x, (f16)b.y, (f16)b.z, (f16)b.w };
        ((half8*)xh)[i] = h;
    }
}

// ---------------- weight transpose -> fp16 ----------------
__global__ __launch_bounds__(256) void transpose_h16(
    const float* __restrict__ W, f16* __restrict__ Ht, int K, int N)
{
    int idx = blockIdx.x * 256 + threadIdx.x;
    if (idx >= N * K) return;
    int n = idx / K, k = idx - n * K;
    Ht[idx] = (f16)W[(size_t)k * N + n];
}

#define OUT_F32 0
#define OUT_H   1
#define OUT_HT  2   // v: row->(b=row/77, si), store [(b*512+col)*96 + si]

// ---------------- big fp16 GEMM: 256x256, counted-vmcnt pipeline ----------
// A fp16 [M][K], B fp16 [N][K]; M,N multiples of 256, K multiple of 32, K>=64.
// launch grid: dim3(N/256, M/256), block 512  (N fastest for A-sharing)
template<bool BIAS, int OUTM>
__global__ __launch_bounds__(512) void gemm_h16_256(
    const f16* __restrict__ A, const f16* __restrict__ B,
    const float* __restrict__ bias, float* __restrict__ C,
    f16* __restrict__ CHalf, int M, int N, int K)
{
    __shared__ f16 smA[2][256 * 32];   // 16 KB each
    __shared__ f16 smB[2][256 * 32];

    const int t = threadIdx.x;
    const int lane = t & 63;
    const int w = t >> 6;            // 0..7
    const int wr = w >> 2;           // 0..1  (M half: 128 rows)
    const int wc = w & 3;            // 0..3  (N quarter: 64 cols)

    // XCD-chunked bijective swizzle (nblk % 8 == 0 here: 512)
    const int f = blockIdx.x + gridDim.x * blockIdx.y;
    const int cpx = (gridDim.x * gridDim.y) >> 3;
    const int logical = (f & 7) * cpx + (f >> 3);
    const int m0 = (logical / gridDim.x) * 256;
    const int n0 = (logical % gridDim.x) * 256;

    const int ar = lane & 15;
    const int kc = (lane >> 4) << 3;
    const int srow = lane >> 2;          // staging row within 16-row chunk
    const int scol = (lane & 3) << 3;    // staging f16 col 0/8/16/24

    f32x4 acc[8][4] = {};

    // 4 gl_lds per thread per K-tile (A: 2 chunks, B: 2 chunks per wave)
    auto STAGE = [&](int buf, int k0) {
        #pragma unroll
        for (int j = 0; j < 2; ++j) {
            const int ci = w * 2 + j;           // chunk 0..15 -> rows ci*16..+15
            const int r = ci * 16 + srow;
            gl_lds16(A + (size_t)(m0 + r) * K + k0 + scol, &smA[buf][ci * 512]);
            gl_lds16(B + (size_t)(n0 + r) * K + k0 + scol, &smB[buf][ci * 512]);
        }
    };

    const int NK = K >> 5;
    // prologue: 2 K-tiles in flight = 8 outstanding loads/thread
    STAGE(0, 0);
    STAGE(1, 32);

    for (int kt = 0; kt < NK; ++kt) {
        // invariant at entry: 8 outstanding (tiles kt, kt+1), except last iter: 4.
        // wait only for tile kt's 4 loads; tile kt+1's stay in flight across
        // the barrier (the whole point -- never vmcnt(0) in the loop).
        if (kt + 1 < NK) asm volatile("s_waitcnt vmcnt(4)" ::: "memory");
        else             asm volatile("s_waitcnt vmcnt(0)" ::: "memory");
        __builtin_amdgcn_s_barrier();          // all waves' tile-kt loads landed
        __builtin_amdgcn_sched_barrier(0);     // keep ds_reads below the wait

        const f16* pA = smA[kt & 1];
        const f16* pB = smB[kt & 1];
        half8 fa[8], fb[4];
        #pragma unroll
        for (int m = 0; m < 8; ++m)
            fa[m] = *(const half8*)(pA + (wr * 128 + m * 16 + ar) * 32 + kc);
        #pragma unroll
        for (int n = 0; n < 4; ++n)
            fb[n] = *(const half8*)(pB + (wc * 64 + n * 16 + ar) * 32 + kc);

        __builtin_amdgcn_s_setprio(1);
        #pragma unroll
        for (int m = 0; m < 8; ++m)
            #pragma unroll
            for (int n = 0; n < 4; ++n)
                acc[m][n] = mfma16h(fa[m], fb[n], acc[m][n]);
        __builtin_amdgcn_s_setprio(0);
        __builtin_amdgcn_s_barrier();          // all waves done reading buf kt&1

        if (kt + 2 < NK) STAGE(kt & 1, (kt + 2) << 5);   // back to 8 in flight
    }

    #pragma unroll
    for (int n = 0; n < 4; ++n) {
        int col = n0 + wc * 64 + n * 16 + ar;
        float bv = 0.f;
        if constexpr (BIAS) bv = bias[col];
        #pragma unroll
        for (int m = 0; m < 8; ++m) {
            #pragma unroll
            for (int r = 0; r < 4; ++r) {
                int row = m0 + wr * 128 + m * 16 + ((lane >> 4) << 2) + r;
                float v = acc[m][n][r] + bv;
                if constexpr (OUTM == OUT_F32) {
                    C[(size_t)row * N + col] = v;
                } else {
                    CHalf[(size_t)row * N + col] = (f16)v;
                }
            }
        }
    }
}

// ---------------- ctx GEMM (kv projections, reg-staged fp32->fp16) ----------
#define PK 40   // padded LDS K-stride

template<int OUTM>
__global__ __launch_bounds__(256) void gemm_ctx(
    const float* __restrict__ A, const f16* __restrict__ Bt,
    f16* __restrict__ CH, int M, int N, int K)
{
    __shared__ f16 lA[128 * PK];
    __shared__ f16 lB[128 * PK];

    const int t = threadIdx.x;
    const int lane = t & 63;
    const int wid = t >> 6;
    const int wr = wid >> 1, wc = wid & 1;
    const int m0 = blockIdx.x * 128, n0 = blockIdx.y * 128;
    const int ar = lane & 15;
    const int kc = (lane >> 4) << 3;

    f32x4 acc[4][4] = {};

    for (int k0 = 0; k0 < K; k0 += 32) {
        #pragma unroll
        for (int it = 0; it < 4; ++it) {
            int idx = t + it * 256;
            int row = idx >> 3;
            int c4 = (idx & 7) << 2;
            int gr = m0 + row;
            float4 v = make_float4(0.f, 0.f, 0.f, 0.f);
            if (gr < M) v = *(const float4*)(A + (size_t)gr * K + k0 + c4);
            *(half4*)(lA + row * PK + c4) = (half4){(f16)v.x, (f16)v.y, (f16)v.z, (f16)v.w};
        }
        #pragma unroll
        for (int it = 0; it < 2; ++it) {
            int idx = t + it * 256;
            int row = idx >> 2;
            int c8 = (idx & 3) << 3;
            *(half8*)(lB + row * PK + c8) =
                *(const half8*)(Bt + (size_t)(n0 + row) * K + k0 + c8);
        }
        __syncthreads();

        half8 fa[4], fb[4];
        #pragma unroll
        for (int m = 0; m < 4; ++m)
            fa[m] = *(const half8*)(lA + (wr * 64 + m * 16 + ar) * PK + kc);
        #pragma unroll
        for (int n = 0; n < 4; ++n)
            fb[n] = *(const half8*)(lB + (wc * 64 + n * 16 + ar) * PK + kc);
        #pragma unroll
        for (int m = 0; m < 4; ++m)
            #pragma unroll
            for (int n = 0; n < 4; ++n)
                acc[m][n] = mfma16h(fa[m], fb[n], acc[m][n]);
        __syncthreads();
    }

    #pragma unroll
    for (int n = 0; n < 4; ++n) {
        int col = n0 + wc * 64 + n * 16 + ar;
        #pragma unroll
        for (int m = 0; m < 4; ++m) {
            #pragma unroll
            for (int r = 0; r < 4; ++r) {
                int row = m0 + wr * 64 + m * 16 + ((lane >> 4) << 2) + r;
                if (row < M) {
                    float v = acc[m][n][r];
                    if constexpr (OUTM == OUT_H) {
                        CH[(size_t)row * N + col] = (f16)v;
                    } else {
                        int bb = row / 77;
                        int si = row - bb * 77;
                        CH[((size_t)bb * 512 + col) * 96 + si] = (f16)v;
                    }
                }
            }
        }
    }
}

// ---------------- MFMA attention (fp16 inputs, fp32 softmax) ----------------
// grid (Sq/128, H, B), block 256 (4 waves, 32 q-rows each).
__global__ __launch_bounds__(256) void attn_h16(
    const f16* __restrict__ q, const f16* __restrict__ k,
    const f16* __restrict__ vT, f16* __restrict__ outA)
{
    constexpr int PST = 104;   // P LDS stride (f16): rows 16B-aligned
    __shared__ f16 sP[4 * 32 * PST];

    const int t = threadIdx.x;
    const int lane = t & 63;
    const int w = t >> 6;
    const int ar = lane & 15;
    const int kg = lane >> 4;
    const int kc = kg << 3;
    const int b = blockIdx.z, head = blockIdx.y;
    const size_t qrow0 = (size_t)b * 4096 + blockIdx.x * 128 + w * 32;

    // ---- scores [32 q][80 si], K-dim = 64 ----
    f32x4 accs[2][5] = {};
    #pragma unroll
    for (int ks = 0; ks < 2; ++ks) {
        const int d = head * 64 + ks * 32 + kc;
        half8 ah[2];
        #pragma unroll
        for (int m = 0; m < 2; ++m)
            ah[m] = *(const half8*)(q + (qrow0 + m * 16 + ar) * 512 + d);
        #pragma unroll
        for (int n = 0; n < 5; ++n) {
            half8 bh = *(const half8*)(k + ((size_t)(b * 77 + n * 16 + ar)) * 512 + d);
            #pragma unroll
            for (int m = 0; m < 2; ++m)
                accs[m][n] = mfma16h(ah[m], bh, accs[m][n]);
        }
    }

    // ---- softmax in registers (rows on 16-lane groups) ----
    #pragma unroll
    for (int m = 0; m < 2; ++m) {
        #pragma unroll
        for (int r = 0; r < 4; ++r) {
            float mx = -1e30f;
            #pragma unroll
            for (int n = 0; n < 5; ++n) {
                float v = accs[m][n][r] * 0.125f;          // * D_HEAD^-0.5
                if (n == 4 && ar >= 13) v = -1e30f;        // mask si >= 77
                accs[m][n][r] = v;
                mx = fmaxf(mx, v);
            }
            mx = fmaxf(mx, __shfl_xor(mx, 1));
            mx = fmaxf(mx, __shfl_xor(mx, 2));
            mx = fmaxf(mx, __shfl_xor(mx, 4));
            mx = fmaxf(mx, __shfl_xor(mx, 8));
            float sum = 0.f;
            #pragma unroll
            for (int n = 0; n < 5; ++n) {
                float e = __expf(accs[m][n][r] - mx);
                accs[m][n][r] = e;
                sum += e;
            }
            sum += __shfl_xor(sum, 1);
            sum += __shfl_xor(sum, 2);
            sum += __shfl_xor(sum, 4);
            sum += __shfl_xor(sum, 8);
            float inv = 1.f / sum;
            #pragma unroll
            for (int n = 0; n < 5; ++n) accs[m][n][r] *= inv;
        }
    }

    // ---- P -> LDS fp16, zero-pad cols 80..103 ----
    f16* myP = sP + w * 32 * PST;
    for (int i = lane; i < 32 * 12; i += 64) {
        int row = i / 12, c = 80 + (i % 12) * 2;
        *(u32*)(myP + row * PST + c) = 0;
    }
    #pragma unroll
    for (int m = 0; m < 2; ++m)
        #pragma unroll
        for (int n = 0; n < 5; ++n)
            #pragma unroll
            for (int r = 0; r < 4; ++r)
                myP[(m * 16 + kg * 4 + r) * PST + n * 16 + ar] = (f16)accs[m][n][r];
    __syncthreads();

    // ---- PV [32 q][64 d], K-dim = 96 (zero-padded) ----
    f32x4 accp[2][4] = {};
    #pragma unroll
    for (int ks = 0; ks < 3; ++ks) {
        half8 pa[2];
        #pragma unroll
        for (int m = 0; m < 2; ++m)
            pa[m] = *(const half8*)(myP + (m * 16 + ar) * PST + ks * 32 + kc);
        #pragma unroll
        for (int n = 0; n < 4; ++n) {
            half8 bh = *(const half8*)(vT + ((size_t)b * 512 + head * 64 + n * 16 + ar) * 96 + ks * 32 + kc);
            #pragma unroll
            for (int m = 0; m < 2; ++m)
                accp[m][n] = mfma16h(pa[m], bh, accp[m][n]);
        }
    }

    // ---- store attn output fp16 ----
    #pragma unroll
    for (int m = 0; m < 2; ++m)
        #pragma unroll
        for (int n = 0; n < 4; ++n)
            #pragma unroll
            for (int r = 0; r < 4; ++r)
                outA[(qrow0 + m * 16 + kg * 4 + r) * 512 + head * 64 + n * 16 + ar]
                    = (f16)accp[m][n][r];
}

extern "C" void kernel_launch(void* const* d_in, const int* in_sizes, int n_in,
                              void* d_out, int out_size, void* d_ws, size_t ws_size,
                              hipStream_t stream)
{
    const float* x    = (const float*)d_in[0];   // [16,4096,512]
    const float* ctx  = (const float*)d_in[1];   // [16,77,768]
    const float* Wq   = (const float*)d_in[2];   // [512,512]
    const float* Wk   = (const float*)d_in[3];   // [768,512]
    const float* Wv   = (const float*)d_in[4];   // [768,512]
    const float* Wout = (const float*)d_in[5];   // [512,512]
    const float* bout = (const float*)d_in[6];   // [512]

    char* ws = (char*)d_ws;
    size_t off = 0;
    auto alloc = [&](size_t bytes) -> void* {
        void* p = ws + off;
        off += (bytes + 255) & ~(size_t)255;
        return p;
    };
    f16* WqT = (f16*)alloc(512 * 512 * 2);
    f16* WkT = (f16*)alloc(768 * 512 * 2);
    f16* WvT = (f16*)alloc(768 * 512 * 2);
    f16* WoT = (f16*)alloc(512 * 512 * 2);
    f16* kbuf = (f16*)alloc((size_t)1240 * 512 * 2);     // 1232 rows + zero pad
    f16* vT   = (f16*)alloc((size_t)16 * 512 * 96 * 2);  // [b][col][si pad 96]
    // 64 MiB block: first holds x fp16, later reused for attn out (x dead by then)
    f16* xh = (f16*)alloc((size_t)65536 * 512 * 2);
    f16* attnA = xh;
    (void)ws_size; (void)in_sizes; (void)n_in; (void)out_size;

    // q fp16 lives in d_out (67 MB of 128 MB), dead before final GEMM writes
    f16* qh = (f16*)d_out;

    // 0. zero pads
    pad_fill<<<dim3(625), dim3(256), 0, stream>>>(vT, kbuf);

    // 1. x -> fp16
    cvt_h16<<<dim3(2048), dim3(256), 0, stream>>>(x, xh, (long)65536 * 512 / 8);

    // 2. weight transposes -> fp16
    transpose_h16<<<dim3(1024), dim3(256), 0, stream>>>(Wq, WqT, 512, 512);
    transpose_h16<<<dim3(1536), dim3(256), 0, stream>>>(Wk, WkT, 768, 512);
    transpose_h16<<<dim3(1536), dim3(256), 0, stream>>>(Wv, WvT, 768, 512);
    transpose_h16<<<dim3(1024), dim3(256), 0, stream>>>(Wout, WoT, 512, 512);

    // 3. k/v projections
    gemm_ctx<OUT_H><<<dim3(10, 4), dim3(256), 0, stream>>>(
        ctx, WkT, kbuf, 1232, 512, 768);
    gemm_ctx<OUT_HT><<<dim3(10, 4), dim3(256), 0, stream>>>(
        ctx, WvT, vT, 1232, 512, 768);

    // 4. q projection: xh @ Wq -> q fp16 in d_out  (grid: N fastest, 512 blocks)
    gemm_h16_256<false, OUT_H><<<dim3(2, 256), dim3(512), 0, stream>>>(
        xh, WqT, (const float*)nullptr, (float*)nullptr, qh, 65536, 512, 512);

    // 5. attention -> attn fp16 (reuses xh buffer)
    attn_h16<<<dim3(32, 8, 16), dim3(256), 0, stream>>>(qh, kbuf, vT, attnA);

    // 6. output projection + bias -> d_out fp32
    gemm_h16_256<true, OUT_F32><<<dim3(2, 256), dim3(512), 0, stream>>>(
        attnA, WoT, bout, (float*)d_out, (f16*)nullptr, 65536, 512, 512);
}

// Round 8
// 308.281 us; speedup vs baseline: 1.0683x; 1.0683x over previous
//
#include <hip/hip_runtime.h>

// CrossAttention: B=16, Sq=4096, Dm=512, Skv=77, Dc=768, H=8, Dh=64, inner=512
// Single-pass fp16 MFMA pipeline.
//   0. pad_fill : zero vT si-pad + kbuf row-pad
//   1. transpose4: all W* fp32 [K][512] -> fp16 [512][K] in one launch  (ws)
//   2. gemm_ctx OUT_H : k = ctx@Wk -> fp16 [1240pad][512]               (ws)
//      gemm_ctx OUT_HT: v = ctx@Wv -> Vt fp16 [16][512][96pad]          (ws)
//   3. gemm_x16 : q = x(fp32)@Wq -> fp16 [65536][512]                   (d_out)
//                 (cvt fused: A staged as f32 via gl_lds with XOR-swizzled
//                  source + swizzled ds_read -> f16 convert in regs)
//   4. attn_h16 : MFMA scores + in-reg fp32 softmax + MFMA PV           (ws)
//   5. gemm_h16 OUT_F32+bias: out = attn@Wout + bout -> fp32            (d_out)
// Big GEMMs: 128^2 tile, dbuf LDS + issue-early global_load_lds (m97/R6
// structure, proven best here) + XCD-chunked swizzle.

typedef unsigned short u16;
typedef unsigned int u32;
typedef _Float16 f16;
typedef __attribute__((ext_vector_type(8))) _Float16 half8;
typedef __attribute__((ext_vector_type(4))) _Float16 half4;
typedef __attribute__((ext_vector_type(4))) float f32x4;

__device__ __forceinline__ f32x4 mfma16h(half8 a, half8 b, f32x4 c) {
    return __builtin_amdgcn_mfma_f32_16x16x32_f16(a, b, c, 0, 0, 0);
}
// async global->LDS, 16B per lane; LDS dest = wave-uniform base + lane*16
__device__ __forceinline__ void gl_lds16(const f16* g, f16* l) {
    __builtin_amdgcn_global_load_lds(
        (const __attribute__((address_space(1))) void*)g,
        (__attribute__((address_space(3))) void*)l, 16, 0, 0);
}
__device__ __forceinline__ void gl_lds16f(const float* g, float* l) {
    __builtin_amdgcn_global_load_lds(
        (const __attribute__((address_space(1))) void*)g,
        (__attribute__((address_space(3))) void*)l, 16, 0, 0);
}

// ---------------- pad fill ----------------
__global__ __launch_bounds__(256) void pad_fill(
    f16* __restrict__ vT, f16* __restrict__ kbuf)
{
    const int nv = 16 * 512 * 19;
    int i = blockIdx.x * 256 + threadIdx.x;
    if (i < nv) {
        int g = i / 19, s = i - g * 19;
        vT[(size_t)g * 96 + 77 + s] = (f16)0.f;
    } else {
        int j = i - nv;
        if (j < 8 * 512) kbuf[(size_t)1232 * 512 + j] = (f16)0.f;
    }
}

// ---------------- all 4 weight transposes -> fp16, one launch ----------------
__global__ __launch_bounds__(256) void transpose4(
    const float* __restrict__ Wq, const float* __restrict__ Wk,
    const float* __restrict__ Wv, const float* __restrict__ Wo,
    f16* __restrict__ WqT, f16* __restrict__ WkT,
    f16* __restrict__ WvT, f16* __restrict__ WoT)
{
    int idx = blockIdx.x * 256 + threadIdx.x;
    const float* W; f16* T; int K; int base;
    if (idx < 262144)        { W = Wq; T = WqT; K = 512; base = 0; }
    else if (idx < 655360)   { W = Wk; T = WkT; K = 768; base = 262144; }
    else if (idx < 1048576)  { W = Wv; T = WvT; K = 768; base = 655360; }
    else if (idx < 1310720)  { W = Wo; T = WoT; K = 512; base = 1048576; }
    else return;
    int j = idx - base;
    int n = j / K, k = j - n * K;
    T[j] = (f16)W[(size_t)k * 512 + n];
}

#define OUT_F32 0
#define OUT_H   1
#define OUT_HT  2   // v: row->(b=row/77, si), store [(b*512+col)*96 + si]

// ---------------- q-proj GEMM: fp32 A via swizzled gl_lds, fused cvt --------
// A fp32 [M][K], B fp16 [N][K]; M,N multiples of 128, K multiple of 32.
// grid dim3(N/128, M/128) (N fastest), block 256.
__global__ __launch_bounds__(256) void gemm_x16(
    const float* __restrict__ A, const f16* __restrict__ B,
    f16* __restrict__ CHalf, int M, int N, int K)
{
    __shared__ float smA[2][128 * 32];   // 16 KB per buf
    __shared__ f16   smB[2][128 * 32];   // 8 KB per buf

    const int t = threadIdx.x;
    const int lane = t & 63;
    const int w = t >> 6;
    const int wr = w >> 1, wc = w & 1;           // 2x2 waves of 64x64

    // XCD-chunked bijective swizzle (2048 blocks, %8==0)
    const int f = blockIdx.x + gridDim.x * blockIdx.y;
    const int cpx = (gridDim.x * gridDim.y) >> 3;
    const int logical = (f & 7) * cpx + (f >> 3);
    const int m0 = (logical / gridDim.x) * 128;
    const int n0 = (logical % gridDim.x) * 128;

    const int ar = lane & 15;
    const int kc = (lane >> 4) << 3;             // element offset 0/8/16/24

    // A staging: 16 chunks of 8 rows x 32 f32; XOR slot swizzle (slot ^= row&7)
    const int rAo = lane >> 3;                   // row in chunk 0..7
    const int sA  = ((lane & 7) ^ rAo) << 2;     // swizzled source f32 col
    // B staging: 8 chunks of 16 rows x 32 f16 (linear, R6 layout)
    const int rBo = lane >> 2;
    const int sB  = (lane & 3) << 3;

    f32x4 acc[4][4] = {};

    auto STAGE = [&](int buf, int k0) {
        #pragma unroll
        for (int j = 0; j < 4; ++j) {
            const int ci = w * 4 + j;            // chunk 0..15 -> rows ci*8..+7
            gl_lds16f(A + (size_t)(m0 + ci * 8 + rAo) * K + k0 + sA,
                      &smA[buf][ci * 256]);
        }
        #pragma unroll
        for (int j = 0; j < 2; ++j) {
            const int ci = w * 2 + j;            // chunk 0..7 -> rows ci*16..+15
            gl_lds16(B + (size_t)(n0 + ci * 16 + rBo) * K + k0 + sB,
                     &smB[buf][ci * 512]);
        }
    };

    const int nk = K >> 5;
    STAGE(0, 0);
    __syncthreads();

    int cur = 0;
    for (int kt = 0; kt < nk; ++kt) {
        if (kt + 1 < nk) STAGE(cur ^ 1, (kt + 1) << 5);

        const float* pA = smA[cur];
        const f16*  pB = smB[cur];

        half8 fa[4], fb[4];
        #pragma unroll
        for (int m = 0; m < 4; ++m) {
            const int row = wr * 64 + m * 16 + ar;
            const int s0 = kc >> 2;              // logical 16B slot (0,2,4,6)
            const float* pr = pA + row * 32;
            f32x4 a0 = *(const f32x4*)(pr + (((s0    ) ^ (row & 7)) << 2));
            f32x4 a1 = *(const f32x4*)(pr + (((s0 + 1) ^ (row & 7)) << 2));
            fa[m] = (half8){(f16)a0.x, (f16)a0.y, (f16)a0.z, (f16)a0.w,
                            (f16)a1.x, (f16)a1.y, (f16)a1.z, (f16)a1.w};
        }
        #pragma unroll
        for (int n = 0; n < 4; ++n)
            fb[n] = *(const half8*)(pB + (wc * 64 + n * 16 + ar) * 32 + kc);

        __builtin_amdgcn_s_setprio(1);
        #pragma unroll
        for (int m = 0; m < 4; ++m)
            #pragma unroll
            for (int n = 0; n < 4; ++n)
                acc[m][n] = mfma16h(fa[m], fb[n], acc[m][n]);
        __builtin_amdgcn_s_setprio(0);
        __syncthreads();
        cur ^= 1;
    }

    #pragma unroll
    for (int n = 0; n < 4; ++n) {
        int col = n0 + wc * 64 + n * 16 + ar;
        #pragma unroll
        for (int m = 0; m < 4; ++m) {
            #pragma unroll
            for (int r = 0; r < 4; ++r) {
                int row = m0 + wr * 64 + m * 16 + ((lane >> 4) << 2) + r;
                CHalf[(size_t)row * N + col] = (f16)acc[m][n][r];
            }
        }
    }
}

// ---------------- big fp16 GEMM (R6 structure): gl_lds dbuf staging --------
// A fp16 [M][K], B fp16 [N][K]; M,N multiples of 128, K multiple of 32.
// launch grid: dim3(N/128, M/128)  (N fastest for A-sharing locality)
template<bool BIAS, int OUTM>
__global__ __launch_bounds__(256) void gemm_h16(
    const f16* __restrict__ A, const f16* __restrict__ B,
    const float* __restrict__ bias, float* __restrict__ C,
    f16* __restrict__ CHalf, int M, int N, int K)
{
    __shared__ f16 sm[2][2][128 * 32];   // [buf][A,B]  32 KB total

    const int t = threadIdx.x;
    const int lane = t & 63;
    const int w = t >> 6;
    const int wr = w >> 1, wc = w & 1;

    const int f = blockIdx.x + gridDim.x * blockIdx.y;
    const int cpx = (gridDim.x * gridDim.y) >> 3;
    const int logical = (f & 7) * cpx + (f >> 3);
    const int m0 = (logical / gridDim.x) * 128;
    const int n0 = (logical % gridDim.x) * 128;

    const int ar = lane & 15;
    const int kc = (lane >> 4) << 3;
    const int srow = lane >> 2;
    const int scol = (lane & 3) << 3;

    f32x4 acc[4][4] = {};

    auto STAGE = [&](int buf, int k0) {
        #pragma unroll
        for (int j = 0; j < 2; ++j) {
            const int ci = w * 2 + j;
            const int r = ci * 16 + srow;
            gl_lds16(A + (size_t)(m0 + r) * K + k0 + scol, &sm[buf][0][ci * 512]);
            gl_lds16(B + (size_t)(n0 + r) * K + k0 + scol, &sm[buf][1][ci * 512]);
        }
    };

    const int nk = K >> 5;
    STAGE(0, 0);
    __syncthreads();

    int cur = 0;
    for (int kt = 0; kt < nk; ++kt) {
        if (kt + 1 < nk) STAGE(cur ^ 1, (kt + 1) << 5);

        const f16* pA = sm[cur][0];
        const f16* pB = sm[cur][1];

        half8 fa[4], fb[4];
        #pragma unroll
        for (int m = 0; m < 4; ++m)
            fa[m] = *(const half8*)(pA + (wr * 64 + m * 16 + ar) * 32 + kc);
        #pragma unroll
        for (int n = 0; n < 4; ++n)
            fb[n] = *(const half8*)(pB + (wc * 64 + n * 16 + ar) * 32 + kc);

        __builtin_amdgcn_s_setprio(1);
        #pragma unroll
        for (int m = 0; m < 4; ++m)
            #pragma unroll
            for (int n = 0; n < 4; ++n)
                acc[m][n] = mfma16h(fa[m], fb[n], acc[m][n]);
        __builtin_amdgcn_s_setprio(0);
        __syncthreads();
        cur ^= 1;
    }

    #pragma unroll
    for (int n = 0; n < 4; ++n) {
        int col = n0 + wc * 64 + n * 16 + ar;
        float bv = 0.f;
        if constexpr (BIAS) bv = bias[col];
        #pragma unroll
        for (int m = 0; m < 4; ++m) {
            #pragma unroll
            for (int r = 0; r < 4; ++r) {
                int row = m0 + wr * 64 + m * 16 + ((lane >> 4) << 2) + r;
                float v = acc[m][n][r] + bv;
                if constexpr (OUTM == OUT_F32) {
                    C[(size_t)row * N + col] = v;
                } else {
                    CHalf[(size_t)row * N + col] = (f16)v;
                }
            }
        }
    }
}

// ---------------- ctx GEMM (kv projections, reg-staged fp32->fp16) ----------
#define PK 40   // padded LDS K-stride

template<int OUTM>
__global__ __launch_bounds__(256) void gemm_ctx(
    const float* __restrict__ A, const f16* __restrict__ Bt,
    f16* __restrict__ CH, int M, int N, int K)
{
    __shared__ f16 lA[128 * PK];
    __shared__ f16 lB[128 * PK];

    const int t = threadIdx.x;
    const int lane = t & 63;
    const int wid = t >> 6;
    const int wr = wid >> 1, wc = wid & 1;
    const int m0 = blockIdx.x * 128, n0 = blockIdx.y * 128;
    const int ar = lane & 15;
    const int kc = (lane >> 4) << 3;

    f32x4 acc[4][4] = {};

    for (int k0 = 0; k0 < K; k0 += 32) {
        #pragma unroll
        for (int it = 0; it < 4; ++it) {
            int idx = t + it * 256;
            int row = idx >> 3;
            int c4 = (idx & 7) << 2;
            int gr = m0 + row;
            float4 v = make_float4(0.f, 0.f, 0.f, 0.f);
            if (gr < M) v = *(const float4*)(A + (size_t)gr * K + k0 + c4);
            *(half4*)(lA + row * PK + c4) = (half4){(f16)v.x, (f16)v.y, (f16)v.z, (f16)v.w};
        }
        #pragma unroll
        for (int it = 0; it < 2; ++it) {
            int idx = t + it * 256;
            int row = idx >> 2;
            int c8 = (idx & 3) << 3;
            *(half8*)(lB + row * PK + c8) =
                *(const half8*)(Bt + (size_t)(n0 + row) * K + k0 + c8);
        }
        __syncthreads();

        half8 fa[4], fb[4];
        #pragma unroll
        for (int m = 0; m < 4; ++m)
            fa[m] = *(const half8*)(lA + (wr * 64 + m * 16 + ar) * PK + kc);
        #pragma unroll
        for (int n = 0; n < 4; ++n)
            fb[n] = *(const half8*)(lB + (wc * 64 + n * 16 + ar) * PK + kc);
        #pragma unroll
        for (int m = 0; m < 4; ++m)
            #pragma unroll
            for (int n = 0; n < 4; ++n)
                acc[m][n] = mfma16h(fa[m], fb[n], acc[m][n]);
        __syncthreads();
    }

    #pragma unroll
    for (int n = 0; n < 4; ++n) {
        int col = n0 + wc * 64 + n * 16 + ar;
        #pragma unroll
        for (int m = 0; m < 4; ++m) {
            #pragma unroll
            for (int r = 0; r < 4; ++r) {
                int row = m0 + wr * 64 + m * 16 + ((lane >> 4) << 2) + r;
                if (row < M) {
                    float v = acc[m][n][r];
                    if constexpr (OUTM == OUT_H) {
                        CH[(size_t)row * N + col] = (f16)v;
                    } else {
                        int bb = row / 77;
                        int si = row - bb * 77;
                        CH[((size_t)bb * 512 + col) * 96 + si] = (f16)v;
                    }
                }
            }
        }
    }
}

// ---------------- MFMA attention (fp16 inputs, fp32 softmax) ----------------
// grid (Sq/128, H, B), block 256 (4 waves, 32 q-rows each).
__global__ __launch_bounds__(256) void attn_h16(
    const f16* __restrict__ q, const f16* __restrict__ k,
    const f16* __restrict__ vT, f16* __restrict__ outA)
{
    constexpr int PST = 104;   // P LDS stride (f16): rows 16B-aligned
    __shared__ f16 sP[4 * 32 * PST];

    const int t = threadIdx.x;
    const int lane = t & 63;
    const int w = t >> 6;
    const int ar = lane & 15;
    const int kg = lane >> 4;
    const int kc = kg << 3;
    const int b = blockIdx.z, head = blockIdx.y;
    const size_t qrow0 = (size_t)b * 4096 + blockIdx.x * 128 + w * 32;

    // ---- scores [32 q][80 si], K-dim = 64 ----
    f32x4 accs[2][5] = {};
    #pragma unroll
    for (int ks = 0; ks < 2; ++ks) {
        const int d = head * 64 + ks * 32 + kc;
        half8 ah[2];
        #pragma unroll
        for (int m = 0; m < 2; ++m)
            ah[m] = *(const half8*)(q + (qrow0 + m * 16 + ar) * 512 + d);
        #pragma unroll
        for (int n = 0; n < 5; ++n) {
            half8 bh = *(const half8*)(k + ((size_t)(b * 77 + n * 16 + ar)) * 512 + d);
            #pragma unroll
            for (int m = 0; m < 2; ++m)
                accs[m][n] = mfma16h(ah[m], bh, accs[m][n]);
        }
    }

    // ---- softmax in registers (rows on 16-lane groups) ----
    #pragma unroll
    for (int m = 0; m < 2; ++m) {
        #pragma unroll
        for (int r = 0; r < 4; ++r) {
            float mx = -1e30f;
            #pragma unroll
            for (int n = 0; n < 5; ++n) {
                float v = accs[m][n][r] * 0.125f;          // * D_HEAD^-0.5
                if (n == 4 && ar >= 13) v = -1e30f;        // mask si >= 77
                accs[m][n][r] = v;
                mx = fmaxf(mx, v);
            }
            mx = fmaxf(mx, __shfl_xor(mx, 1));
            mx = fmaxf(mx, __shfl_xor(mx, 2));
            mx = fmaxf(mx, __shfl_xor(mx, 4));
            mx = fmaxf(mx, __shfl_xor(mx, 8));
            float sum = 0.f;
            #pragma unroll
            for (int n = 0; n < 5; ++n) {
                float e = __expf(accs[m][n][r] - mx);
                accs[m][n][r] = e;
                sum += e;
            }
            sum += __shfl_xor(sum, 1);
            sum += __shfl_xor(sum, 2);
            sum += __shfl_xor(sum, 4);
            sum += __shfl_xor(sum, 8);
            float inv = 1.f / sum;
            #pragma unroll
            for (int n = 0; n < 5; ++n) accs[m][n][r] *= inv;
        }
    }

    // ---- P -> LDS fp16, zero-pad cols 80..103 ----
    f16* myP = sP + w * 32 * PST;
    for (int i = lane; i < 32 * 12; i += 64) {
        int row = i / 12, c = 80 + (i % 12) * 2;
        *(u32*)(myP + row * PST + c) = 0;
    }
    #pragma unroll
    for (int m = 0; m < 2; ++m)
        #pragma unroll
        for (int n = 0; n < 5; ++n)
            #pragma unroll
            for (int r = 0; r < 4; ++r)
                myP[(m * 16 + kg * 4 + r) * PST + n * 16 + ar] = (f16)accs[m][n][r];
    __syncthreads();

    // ---- PV [32 q][64 d], K-dim = 96 (zero-padded) ----
    f32x4 accp[2][4] = {};
    #pragma unroll
    for (int ks = 0; ks < 3; ++ks) {
        half8 pa[2];
        #pragma unroll
        for (int m = 0; m < 2; ++m)
            pa[m] = *(const half8*)(myP + (m * 16 + ar) * PST + ks * 32 + kc);
        #pragma unroll
        for (int n = 0; n < 4; ++n) {
            half8 bh = *(const half8*)(vT + ((size_t)b * 512 + head * 64 + n * 16 + ar) * 96 + ks * 32 + kc);
            #pragma unroll
            for (int m = 0; m < 2; ++m)
                accp[m][n] = mfma16h(pa[m], bh, accp[m][n]);
        }
    }

    // ---- store attn output fp16 ----
    #pragma unroll
    for (int m = 0; m < 2; ++m)
        #pragma unroll
        for (int n = 0; n < 4; ++n)
            #pragma unroll
            for (int r = 0; r < 4; ++r)
                outA[(qrow0 + m * 16 + kg * 4 + r) * 512 + head * 64 + n * 16 + ar]
                    = (f16)accp[m][n][r];
}

extern "C" void kernel_launch(void* const* d_in, const int* in_sizes, int n_in,
                              void* d_out, int out_size, void* d_ws, size_t ws_size,
                              hipStream_t stream)
{
    const float* x    = (const float*)d_in[0];   // [16,4096,512]
    const float* ctx  = (const float*)d_in[1];   // [16,77,768]
    const float* Wq   = (const float*)d_in[2];   // [512,512]
    const float* Wk   = (const float*)d_in[3];   // [768,512]
    const float* Wv   = (const float*)d_in[4];   // [768,512]
    const float* Wout = (const float*)d_in[5];   // [512,512]
    const float* bout = (const float*)d_in[6];   // [512]

    char* ws = (char*)d_ws;
    size_t off = 0;
    auto alloc = [&](size_t bytes) -> void* {
        void* p = ws + off;
        off += (bytes + 255) & ~(size_t)255;
        return p;
    };
    f16* WqT = (f16*)alloc(512 * 512 * 2);
    f16* WkT = (f16*)alloc(768 * 512 * 2);
    f16* WvT = (f16*)alloc(768 * 512 * 2);
    f16* WoT = (f16*)alloc(512 * 512 * 2);
    f16* kbuf = (f16*)alloc((size_t)1240 * 512 * 2);     // 1232 rows + zero pad
    f16* vT   = (f16*)alloc((size_t)16 * 512 * 96 * 2);  // [b][col][si pad 96]
    f16* attnA = (f16*)alloc((size_t)65536 * 512 * 2);   // attn output (64 MiB)
    (void)ws_size; (void)in_sizes; (void)n_in; (void)out_size;

    // q fp16 lives in d_out (67 MB of 128 MB), dead before final GEMM writes
    f16* qh = (f16*)d_out;

    // 0. zero pads
    pad_fill<<<dim3(625), dim3(256), 0, stream>>>(vT, kbuf);

    // 1. weight transposes -> fp16 (one launch)
    transpose4<<<dim3(5120), dim3(256), 0, stream>>>(
        Wq, Wk, Wv, Wout, WqT, WkT, WvT, WoT);

    // 2. k/v projections
    gemm_ctx<OUT_H><<<dim3(10, 4), dim3(256), 0, stream>>>(
        ctx, WkT, kbuf, 1232, 512, 768);
    gemm_ctx<OUT_HT><<<dim3(10, 4), dim3(256), 0, stream>>>(
        ctx, WvT, vT, 1232, 512, 768);

    // 3. q projection (cvt fused): x fp32 @ WqT -> q fp16 in d_out
    gemm_x16<<<dim3(4, 512), dim3(256), 0, stream>>>(
        x, WqT, qh, 65536, 512, 512);

    // 4. attention -> attn fp16
    attn_h16<<<dim3(32, 8, 16), dim3(256), 0, stream>>>(qh, kbuf, vT, attnA);

    // 5. output projection + bias -> d_out fp32
    gemm_h16<true, OUT_F32><<<dim3(4, 512), dim3(256), 0, stream>>>(
        attnA, WoT, bout, (float*)d_out, (f16*)nullptr, 65536, 512, 512);
}

// Round 9
// 306.954 us; speedup vs baseline: 1.0730x; 1.0043x over previous
//
#include <hip/hip_runtime.h>

// CrossAttention: B=16, Sq=4096, Dm=512, Skv=77, Dc=768, H=8, Dh=64, inner=512
// Single-pass fp16 MFMA pipeline.
//   0. pad_fill : zero vT si-pad + kbuf row-pad
//   1. transpose4: all W* fp32 [K][512] -> fp16 [512][K] in one launch  (ws)
//   2. gemm_ctx OUT_H : k = ctx@Wk -> fp16 [1240pad][512]               (ws)
//      gemm_ctx OUT_HT: v = ctx@Wv -> Vt fp16 [16][512][96pad]          (ws)
//   3. gemm_x16 : q = x(fp32)@Wq -> fp16 [65536][512]                   (d_out)
//                 (cvt fused: A reg-staged async f32->f16, fp16 LDS;
//                  B via global_load_lds; R6 dbuf 2-barrier loop)
//   4. attn_h16 : MFMA scores + in-reg fp32 softmax + MFMA PV           (ws)
//   5. gemm_h16 OUT_F32+bias: out = attn@Wout + bout -> fp32            (d_out)

typedef unsigned short u16;
typedef unsigned int u32;
typedef _Float16 f16;
typedef __attribute__((ext_vector_type(8))) _Float16 half8;
typedef __attribute__((ext_vector_type(4))) _Float16 half4;
typedef __attribute__((ext_vector_type(4))) float f32x4;

__device__ __forceinline__ f32x4 mfma16h(half8 a, half8 b, f32x4 c) {
    return __builtin_amdgcn_mfma_f32_16x16x32_f16(a, b, c, 0, 0, 0);
}
// async global->LDS, 16B per lane; LDS dest = wave-uniform base + lane*16
__device__ __forceinline__ void gl_lds16(const f16* g, f16* l) {
    __builtin_amdgcn_global_load_lds(
        (const __attribute__((address_space(1))) void*)g,
        (__attribute__((address_space(3))) void*)l, 16, 0, 0);
}

// ---------------- pad fill ----------------
__global__ __launch_bounds__(256) void pad_fill(
    f16* __restrict__ vT, f16* __restrict__ kbuf)
{
    const int nv = 16 * 512 * 19;
    int i = blockIdx.x * 256 + threadIdx.x;
    if (i < nv) {
        int g = i / 19, s = i - g * 19;
        vT[(size_t)g * 96 + 77 + s] = (f16)0.f;
    } else {
        int j = i - nv;
        if (j < 8 * 512) kbuf[(size_t)1232 * 512 + j] = (f16)0.f;
    }
}

// ---------------- all 4 weight transposes -> fp16, one launch ----------------
__global__ __launch_bounds__(256) void transpose4(
    const float* __restrict__ Wq, const float* __restrict__ Wk,
    const float* __restrict__ Wv, const float* __restrict__ Wo,
    f16* __restrict__ WqT, f16* __restrict__ WkT,
    f16* __restrict__ WvT, f16* __restrict__ WoT)
{
    int idx = blockIdx.x * 256 + threadIdx.x;
    const float* W; f16* T; int K; int base;
    if (idx < 262144)        { W = Wq; T = WqT; K = 512; base = 0; }
    else if (idx < 655360)   { W = Wk; T = WkT; K = 768; base = 262144; }
    else if (idx < 1048576)  { W = Wv; T = WvT; K = 768; base = 655360; }
    else if (idx < 1310720)  { W = Wo; T = WoT; K = 512; base = 1048576; }
    else return;
    int j = idx - base;
    int n = j / K, k = j - n * K;
    T[j] = (f16)W[(size_t)k * 512 + n];
}

#define OUT_F32 0
#define OUT_H   1
#define OUT_HT  2   // v: row->(b=row/77, si), store [(b*512+col)*96 + si]

// ---------------- q-proj GEMM: fused fp32->fp16, reg-staged A --------------
// A fp32 [M][K], B fp16 [N][K]; M,N multiples of 128, K multiple of 32.
// grid dim3(N/128, M/128) (N fastest), block 256.
__global__ __launch_bounds__(256) void gemm_x16(
    const float* __restrict__ A, const f16* __restrict__ B,
    f16* __restrict__ CHalf, int M, int N, int K)
{
    __shared__ f16 smA[2][128 * 32];   // 8 KB per buf
    __shared__ f16 smB[2][128 * 32];   // 8 KB per buf

    const int t = threadIdx.x;
    const int lane = t & 63;
    const int w = t >> 6;
    const int wr = w >> 1, wc = w & 1;           // 2x2 waves of 64x64

    // XCD-chunked bijective swizzle (2048 blocks, %8==0)
    const int f = blockIdx.x + gridDim.x * blockIdx.y;
    const int cpx = (gridDim.x * gridDim.y) >> 3;
    const int logical = (f & 7) * cpx + (f >> 3);
    const int m0 = (logical / gridDim.x) * 128;
    const int n0 = (logical % gridDim.x) * 128;

    const int ar = lane & 15;
    const int kc = (lane >> 4) << 3;             // f16 element offset 0/8/16/24

    // A reg staging: idx = t + it*256 over 1024 f32x4 chunks (128 rows x 32)
    const int arow = t >> 3;                     // row 0..31 (+ it*32)
    const int ac4  = (t & 7) << 2;               // f32 col 0/4/.../28
    // B staging via gl_lds: 8 chunks of 16 rows x 32 f16
    const int rBo = lane >> 2;
    const int sB  = (lane & 3) << 3;

    f32x4 acc[4][4] = {};
    f32x4 rA[4];

    auto LOAD_A = [&](int k0) {
        #pragma unroll
        for (int it = 0; it < 4; ++it)
            rA[it] = *(const f32x4*)(A + (size_t)(m0 + arow + it * 32) * K + k0 + ac4);
    };
    auto WRITE_A = [&](int buf) {
        #pragma unroll
        for (int it = 0; it < 4; ++it) {
            half4 h = {(f16)rA[it].x, (f16)rA[it].y, (f16)rA[it].z, (f16)rA[it].w};
            *(half4*)(&smA[buf][(arow + it * 32) * 32 + ac4]) = h;
        }
    };
    auto STAGE_B = [&](int buf, int k0) {
        #pragma unroll
        for (int j = 0; j < 2; ++j) {
            const int ci = w * 2 + j;            // chunk 0..7 -> rows ci*16..+15
            gl_lds16(B + (size_t)(n0 + ci * 16 + rBo) * K + k0 + sB,
                     &smB[buf][ci * 512]);
        }
    };

    const int nk = K >> 5;
    LOAD_A(0);
    STAGE_B(0, 0);
    WRITE_A(0);          // compiler waits rA here
    __syncthreads();     // drains gl_lds + ds_writes

    int cur = 0;
    for (int kt = 0; kt < nk; ++kt) {
        // issue next tile's loads early: they fly under ds_read + MFMA
        if (kt + 1 < nk) {
            LOAD_A((kt + 1) << 5);
            STAGE_B(cur ^ 1, (kt + 1) << 5);
        }

        const f16* pA = smA[cur];
        const f16* pB = smB[cur];
        half8 fa[4], fb[4];
        #pragma unroll
        for (int m = 0; m < 4; ++m)
            fa[m] = *(const half8*)(pA + (wr * 64 + m * 16 + ar) * 32 + kc);
        #pragma unroll
        for (int n = 0; n < 4; ++n)
            fb[n] = *(const half8*)(pB + (wc * 64 + n * 16 + ar) * 32 + kc);

        __builtin_amdgcn_s_setprio(1);
        #pragma unroll
        for (int m = 0; m < 4; ++m)
            #pragma unroll
            for (int n = 0; n < 4; ++n)
                acc[m][n] = mfma16h(fa[m], fb[n], acc[m][n]);
        __builtin_amdgcn_s_setprio(0);

        if (kt + 1 < nk) WRITE_A(cur ^ 1);   // vmcnt wait lands after MFMA
        __syncthreads();
        cur ^= 1;
    }

    #pragma unroll
    for (int n = 0; n < 4; ++n) {
        int col = n0 + wc * 64 + n * 16 + ar;
        #pragma unroll
        for (int m = 0; m < 4; ++m) {
            #pragma unroll
            for (int r = 0; r < 4; ++r) {
                int row = m0 + wr * 64 + m * 16 + ((lane >> 4) << 2) + r;
                CHalf[(size_t)row * N + col] = (f16)acc[m][n][r];
            }
        }
    }
}

// ---------------- big fp16 GEMM (R6 structure): gl_lds dbuf staging --------
// A fp16 [M][K], B fp16 [N][K]; M,N multiples of 128, K multiple of 32.
// launch grid: dim3(N/128, M/128)  (N fastest for A-sharing locality)
template<bool BIAS, int OUTM>
__global__ __launch_bounds__(256) void gemm_h16(
    const f16* __restrict__ A, const f16* __restrict__ B,
    const float* __restrict__ bias, float* __restrict__ C,
    f16* __restrict__ CHalf, int M, int N, int K)
{
    __shared__ f16 sm[2][2][128 * 32];   // [buf][A,B]  32 KB total

    const int t = threadIdx.x;
    const int lane = t & 63;
    const int w = t >> 6;
    const int wr = w >> 1, wc = w & 1;

    const int f = blockIdx.x + gridDim.x * blockIdx.y;
    const int cpx = (gridDim.x * gridDim.y) >> 3;
    const int logical = (f & 7) * cpx + (f >> 3);
    const int m0 = (logical / gridDim.x) * 128;
    const int n0 = (logical % gridDim.x) * 128;

    const int ar = lane & 15;
    const int kc = (lane >> 4) << 3;
    const int srow = lane >> 2;
    const int scol = (lane & 3) << 3;

    f32x4 acc[4][4] = {};

    auto STAGE = [&](int buf, int k0) {
        #pragma unroll
        for (int j = 0; j < 2; ++j) {
            const int ci = w * 2 + j;
            const int r = ci * 16 + srow;
            gl_lds16(A + (size_t)(m0 + r) * K + k0 + scol, &sm[buf][0][ci * 512]);
            gl_lds16(B + (size_t)(n0 + r) * K + k0 + scol, &sm[buf][1][ci * 512]);
        }
    };

    const int nk = K >> 5;
    STAGE(0, 0);
    __syncthreads();

    int cur = 0;
    for (int kt = 0; kt < nk; ++kt) {
        if (kt + 1 < nk) STAGE(cur ^ 1, (kt + 1) << 5);

        const f16* pA = sm[cur][0];
        const f16* pB = sm[cur][1];

        half8 fa[4], fb[4];
        #pragma unroll
        for (int m = 0; m < 4; ++m)
            fa[m] = *(const half8*)(pA + (wr * 64 + m * 16 + ar) * 32 + kc);
        #pragma unroll
        for (int n = 0; n < 4; ++n)
            fb[n] = *(const half8*)(pB + (wc * 64 + n * 16 + ar) * 32 + kc);

        __builtin_amdgcn_s_setprio(1);
        #pragma unroll
        for (int m = 0; m < 4; ++m)
            #pragma unroll
            for (int n = 0; n < 4; ++n)
                acc[m][n] = mfma16h(fa[m], fb[n], acc[m][n]);
        __builtin_amdgcn_s_setprio(0);
        __syncthreads();
        cur ^= 1;
    }

    #pragma unroll
    for (int n = 0; n < 4; ++n) {
        int col = n0 + wc * 64 + n * 16 + ar;
        float bv = 0.f;
        if constexpr (BIAS) bv = bias[col];
        #pragma unroll
        for (int m = 0; m < 4; ++m) {
            #pragma unroll
            for (int r = 0; r < 4; ++r) {
                int row = m0 + wr * 64 + m * 16 + ((lane >> 4) << 2) + r;
                float v = acc[m][n][r] + bv;
                if constexpr (OUTM == OUT_F32) {
                    C[(size_t)row * N + col] = v;
                } else {
                    CHalf[(size_t)row * N + col] = (f16)v;
                }
            }
        }
    }
}

// ---------------- ctx GEMM (kv projections, reg-staged fp32->fp16) ----------
#define PK 40   // padded LDS K-stride

template<int OUTM>
__global__ __launch_bounds__(256) void gemm_ctx(
    const float* __restrict__ A, const f16* __restrict__ Bt,
    f16* __restrict__ CH, int M, int N, int K)
{
    __shared__ f16 lA[128 * PK];
    __shared__ f16 lB[128 * PK];

    const int t = threadIdx.x;
    const int lane = t & 63;
    const int wid = t >> 6;
    const int wr = wid >> 1, wc = wid & 1;
    const int m0 = blockIdx.x * 128, n0 = blockIdx.y * 128;
    const int ar = lane & 15;
    const int kc = (lane >> 4) << 3;

    f32x4 acc[4][4] = {};

    for (int k0 = 0; k0 < K; k0 += 32) {
        #pragma unroll
        for (int it = 0; it < 4; ++it) {
            int idx = t + it * 256;
            int row = idx >> 3;
            int c4 = (idx & 7) << 2;
            int gr = m0 + row;
            float4 v = make_float4(0.f, 0.f, 0.f, 0.f);
            if (gr < M) v = *(const float4*)(A + (size_t)gr * K + k0 + c4);
            *(half4*)(lA + row * PK + c4) = (half4){(f16)v.x, (f16)v.y, (f16)v.z, (f16)v.w};
        }
        #pragma unroll
        for (int it = 0; it < 2; ++it) {
            int idx = t + it * 256;
            int row = idx >> 2;
            int c8 = (idx & 3) << 3;
            *(half8*)(lB + row * PK + c8) =
                *(const half8*)(Bt + (size_t)(n0 + row) * K + k0 + c8);
        }
        __syncthreads();

        half8 fa[4], fb[4];
        #pragma unroll
        for (int m = 0; m < 4; ++m)
            fa[m] = *(const half8*)(lA + (wr * 64 + m * 16 + ar) * PK + kc);
        #pragma unroll
        for (int n = 0; n < 4; ++n)
            fb[n] = *(const half8*)(lB + (wc * 64 + n * 16 + ar) * PK + kc);
        #pragma unroll
        for (int m = 0; m < 4; ++m)
            #pragma unroll
            for (int n = 0; n < 4; ++n)
                acc[m][n] = mfma16h(fa[m], fb[n], acc[m][n]);
        __syncthreads();
    }

    #pragma unroll
    for (int n = 0; n < 4; ++n) {
        int col = n0 + wc * 64 + n * 16 + ar;
        #pragma unroll
        for (int m = 0; m < 4; ++m) {
            #pragma unroll
            for (int r = 0; r < 4; ++r) {
                int row = m0 + wr * 64 + m * 16 + ((lane >> 4) << 2) + r;
                if (row < M) {
                    float v = acc[m][n][r];
                    if constexpr (OUTM == OUT_H) {
                        CH[(size_t)row * N + col] = (f16)v;
                    } else {
                        int bb = row / 77;
                        int si = row - bb * 77;
                        CH[((size_t)bb * 512 + col) * 96 + si] = (f16)v;
                    }
                }
            }
        }
    }
}

// ---------------- MFMA attention (fp16 inputs, fp32 softmax) ----------------
// grid (Sq/128, H, B), block 256 (4 waves, 32 q-rows each).
__global__ __launch_bounds__(256) void attn_h16(
    const f16* __restrict__ q, const f16* __restrict__ k,
    const f16* __restrict__ vT, f16* __restrict__ outA)
{
    constexpr int PST = 104;   // P LDS stride (f16): rows 16B-aligned
    __shared__ f16 sP[4 * 32 * PST];

    const int t = threadIdx.x;
    const int lane = t & 63;
    const int w = t >> 6;
    const int ar = lane & 15;
    const int kg = lane >> 4;
    const int kc = kg << 3;
    const int b = blockIdx.z, head = blockIdx.y;
    const size_t qrow0 = (size_t)b * 4096 + blockIdx.x * 128 + w * 32;

    // ---- scores [32 q][80 si], K-dim = 64 ----
    f32x4 accs[2][5] = {};
    #pragma unroll
    for (int ks = 0; ks < 2; ++ks) {
        const int d = head * 64 + ks * 32 + kc;
        half8 ah[2];
        #pragma unroll
        for (int m = 0; m < 2; ++m)
            ah[m] = *(const half8*)(q + (qrow0 + m * 16 + ar) * 512 + d);
        #pragma unroll
        for (int n = 0; n < 5; ++n) {
            half8 bh = *(const half8*)(k + ((size_t)(b * 77 + n * 16 + ar)) * 512 + d);
            #pragma unroll
            for (int m = 0; m < 2; ++m)
                accs[m][n] = mfma16h(ah[m], bh, accs[m][n]);
        }
    }

    // ---- softmax in registers (rows on 16-lane groups) ----
    #pragma unroll
    for (int m = 0; m < 2; ++m) {
        #pragma unroll
        for (int r = 0; r < 4; ++r) {
            float mx = -1e30f;
            #pragma unroll
            for (int n = 0; n < 5; ++n) {
                float v = accs[m][n][r] * 0.125f;          // * D_HEAD^-0.5
                if (n == 4 && ar >= 13) v = -1e30f;        // mask si >= 77
                accs[m][n][r] = v;
                mx = fmaxf(mx, v);
            }
            mx = fmaxf(mx, __shfl_xor(mx, 1));
            mx = fmaxf(mx, __shfl_xor(mx, 2));
            mx = fmaxf(mx, __shfl_xor(mx, 4));
            mx = fmaxf(mx, __shfl_xor(mx, 8));
            float sum = 0.f;
            #pragma unroll
            for (int n = 0; n < 5; ++n) {
                float e = __expf(accs[m][n][r] - mx);
                accs[m][n][r] = e;
                sum += e;
            }
            sum += __shfl_xor(sum, 1);
            sum += __shfl_xor(sum, 2);
            sum += __shfl_xor(sum, 4);
            sum += __shfl_xor(sum, 8);
            float inv = 1.f / sum;
            #pragma unroll
            for (int n = 0; n < 5; ++n) accs[m][n][r] *= inv;
        }
    }

    // ---- P -> LDS fp16, zero-pad cols 80..103 ----
    f16* myP = sP + w * 32 * PST;
    for (int i = lane; i < 32 * 12; i += 64) {
        int row = i / 12, c = 80 + (i % 12) * 2;
        *(u32*)(myP + row * PST + c) = 0;
    }
    #pragma unroll
    for (int m = 0; m < 2; ++m)
        #pragma unroll
        for (int n = 0; n < 5; ++n)
            #pragma unroll
            for (int r = 0; r < 4; ++r)
                myP[(m * 16 + kg * 4 + r) * PST + n * 16 + ar] = (f16)accs[m][n][r];
    __syncthreads();

    // ---- PV [32 q][64 d], K-dim = 96 (zero-padded) ----
    f32x4 accp[2][4] = {};
    #pragma unroll
    for (int ks = 0; ks < 3; ++ks) {
        half8 pa[2];
        #pragma unroll
        for (int m = 0; m < 2; ++m)
            pa[m] = *(const half8*)(myP + (m * 16 + ar) * PST + ks * 32 + kc);
        #pragma unroll
        for (int n = 0; n < 4; ++n) {
            half8 bh = *(const half8*)(vT + ((size_t)b * 512 + head * 64 + n * 16 + ar) * 96 + ks * 32 + kc);
            #pragma unroll
            for (int m = 0; m < 2; ++m)
                accp[m][n] = mfma16h(pa[m], bh, accp[m][n]);
        }
    }

    // ---- store attn output fp16 ----
    #pragma unroll
    for (int m = 0; m < 2; ++m)
        #pragma unroll
        for (int n = 0; n < 4; ++n)
            #pragma unroll
            for (int r = 0; r < 4; ++r)
                outA[(qrow0 + m * 16 + kg * 4 + r) * 512 + head * 64 + n * 16 + ar]
                    = (f16)accp[m][n][r];
}

extern "C" void kernel_launch(void* const* d_in, const int* in_sizes, int n_in,
                              void* d_out, int out_size, void* d_ws, size_t ws_size,
                              hipStream_t stream)
{
    const float* x    = (const float*)d_in[0];   // [16,4096,512]
    const float* ctx  = (const float*)d_in[1];   // [16,77,768]
    const float* Wq   = (const float*)d_in[2];   // [512,512]
    const float* Wk   = (const float*)d_in[3];   // [768,512]
    const float* Wv   = (const float*)d_in[4];   // [768,512]
    const float* Wout = (const float*)d_in[5];   // [512,512]
    const float* bout = (const float*)d_in[6];   // [512]

    char* ws = (char*)d_ws;
    size_t off = 0;
    auto alloc = [&](size_t bytes) -> void* {
        void* p = ws + off;
        off += (bytes + 255) & ~(size_t)255;
        return p;
    };
    f16* WqT = (f16*)alloc(512 * 512 * 2);
    f16* WkT = (f16*)alloc(768 * 512 * 2);
    f16* WvT = (f16*)alloc(768 * 512 * 2);
    f16* WoT = (f16*)alloc(512 * 512 * 2);
    f16* kbuf = (f16*)alloc((size_t)1240 * 512 * 2);     // 1232 rows + zero pad
    f16* vT   = (f16*)alloc((size_t)16 * 512 * 96 * 2);  // [b][col][si pad 96]
    f16* attnA = (f16*)alloc((size_t)65536 * 512 * 2);   // attn output (64 MiB)
    (void)ws_size; (void)in_sizes; (void)n_in; (void)out_size;

    // q fp16 lives in d_out (67 MB of 128 MB), dead before final GEMM writes
    f16* qh = (f16*)d_out;

    // 0. zero pads
    pad_fill<<<dim3(625), dim3(256), 0, stream>>>(vT, kbuf);

    // 1. weight transposes -> fp16 (one launch)
    transpose4<<<dim3(5120), dim3(256), 0, stream>>>(
        Wq, Wk, Wv, Wout, WqT, WkT, WvT, WoT);

    // 2. k/v projections
    gemm_ctx<OUT_H><<<dim3(10, 4), dim3(256), 0, stream>>>(
        ctx, WkT, kbuf, 1232, 512, 768);
    gemm_ctx<OUT_HT><<<dim3(10, 4), dim3(256), 0, stream>>>(
        ctx, WvT, vT, 1232, 512, 768);

    // 3. q projection (cvt fused): x fp32 @ WqT -> q fp16 in d_out
    gemm_x16<<<dim3(4, 512), dim3(256), 0, stream>>>(
        x, WqT, qh, 65536, 512, 512);

    // 4. attention -> attn fp16
    attn_h16<<<dim3(32, 8, 16), dim3(256), 0, stream>>>(qh, kbuf, vT, attnA);

    // 5. output projection + bias -> d_out fp32
    gemm_h16<true, OUT_F32><<<dim3(4, 512), dim3(256), 0, stream>>>(
        attnA, WoT, bout, (float*)d_out, (f16*)nullptr, 65536, 512, 512);
}